// Round 1
// baseline (869.217 us; speedup 1.0000x reference)
//
#include <hip/hip_runtime.h>
#include <math.h>

// Problem constants: T=1024, B=8, H=8, N=32. D = H*N*N = 8192.
#define T_STEPS 1024
#define NBH     64          // B*H
#define NTILE   65536       // T*B*H
#define NCHAIN  2048        // B*H*N independent row-chains

static __device__ __forceinline__ float fast_rcp(float x) {
  return __builtin_amdgcn_rcpf(x);
}
static __device__ __forceinline__ float fast_sigmoid(float x) {
  return fast_rcp(1.0f + __expf(-x));
}
static __device__ __forceinline__ float fast_tanh(float x) {
  // tanh(x) = 1 - 2/(1+e^{2x}); exp->inf gives 1, exp->0 gives -1 (correct limits)
  return 1.0f - 2.0f * fast_rcp(1.0f + __expf(2.0f * x));
}

// ---------------------------------------------------------------------------
// Phase A: per-(t,b,h) tile statistics. One 256-thread block per 32x32 tile.
// Outputs: knorm[tile][32], v[tile][32], beta[tile].
// Fully parallel over 65536 tiles; memory-bound on reading x (256 MB).
// ---------------------------------------------------------------------------
__global__ __launch_bounds__(256) void stats_kernel(
    const float* __restrict__ x, const float* __restrict__ scale_p,
    const float* __restrict__ bias_p, float* __restrict__ kn,
    float* __restrict__ vv, float* __restrict__ bb) {
  const int tile = blockIdx.x;        // = t*64 + bh
  const int tid  = threadIdx.x;       // 0..255
  const int w    = tid >> 6;          // wave 0..3
  const int l    = tid & 63;          // lane

  // thread covers A[i][j0..j0+3], i = tid/8, j0 = (tid%8)*4
  const float4 a = ((const float4*)(x + (size_t)tile * 1024))[tid];

  // row partial sum, reduce across the 8 contiguous lanes sharing row i
  float rsum = (a.x + a.y) + (a.z + a.w);
  rsum += __shfl_xor(rsum, 1);
  rsum += __shfl_xor(rsum, 2);
  rsum += __shfl_xor(rsum, 4);

  // column partials: 4 columns per thread; reduce across stride-8 lanes
  // (lanes differing in bits 3,4,5 share the same columns within a wave)
  float c0 = a.x, c1 = a.y, c2 = a.z, c3 = a.w;
  c0 += __shfl_xor(c0, 8);  c1 += __shfl_xor(c1, 8);
  c2 += __shfl_xor(c2, 8);  c3 += __shfl_xor(c3, 8);
  c0 += __shfl_xor(c0, 16); c1 += __shfl_xor(c1, 16);
  c2 += __shfl_xor(c2, 16); c3 += __shfl_xor(c3, 16);
  c0 += __shfl_xor(c0, 32); c1 += __shfl_xor(c1, 32);
  c2 += __shfl_xor(c2, 32); c3 += __shfl_xor(c3, 32);

  __shared__ float rs[32];      // full row sums
  __shared__ float cp[4][32];   // per-wave column partials (8 rows each)

  const int i = tid >> 3;
  if ((l & 7) == 0) rs[i] = rsum;
  if (l < 8) {
    const int j0 = l * 4;
    cp[w][j0 + 0] = c0; cp[w][j0 + 1] = c1;
    cp[w][j0 + 2] = c2; cp[w][j0 + 3] = c3;
  }
  __syncthreads();

  if (tid < 64) {
    float s;
    if (tid < 32) {
      s = rs[tid];                               // row sum -> k path
    } else {
      const int j = tid - 32;                    // col sum -> v path
      s = (cp[0][j] + cp[1][j]) + (cp[2][j] + cp[3][j]);
    }
    const float k = s * (1.0f / 32.0f);
    // reduce sum(k) and sum(k^2) across lanes 0-31 (masks<=16 stay in-half;
    // upper half computes unused values harmlessly)
    float sumk = k, sumk2 = k * k;
    sumk += __shfl_xor(sumk, 1);  sumk2 += __shfl_xor(sumk2, 1);
    sumk += __shfl_xor(sumk, 2);  sumk2 += __shfl_xor(sumk2, 2);
    sumk += __shfl_xor(sumk, 4);  sumk2 += __shfl_xor(sumk2, 4);
    sumk += __shfl_xor(sumk, 8);  sumk2 += __shfl_xor(sumk2, 8);
    sumk += __shfl_xor(sumk, 16); sumk2 += __shfl_xor(sumk2, 16);

    if (tid < 32) {
      const float norm = sqrtf(sumk2);
      kn[(size_t)tile * 32 + tid] = k * fast_rcp(norm + 1e-6f);
      if (tid == 0) {
        const float mean = sumk * (1.0f / 32.0f);  // overall tile mean
        const float z = scale_p[0] * mean + bias_p[0];
        bb[tile] = fast_sigmoid(z);
      }
    } else {
      vv[(size_t)tile * 32 + (tid - 32)] = k;      // v[j] = colsum/32
    }
  }
}

// ---------------------------------------------------------------------------
// Phase B: serial scan. 2048 independent row-chains (b,h,i), each owned by a
// 32-lane half-wave (lane = column j). No barriers, no LDS. knorm/v/beta for
// step t+1 are prefetched (independent of the scan state).
// 256 blocks x 256 threads = 8 chains/block, ~1 wave per SIMD chip-wide.
// ---------------------------------------------------------------------------
__global__ __launch_bounds__(256) void scan_kernel(
    const float* __restrict__ S0, const float* __restrict__ kn,
    const float* __restrict__ vv, const float* __restrict__ bb,
    float* __restrict__ out, float* __restrict__ Sfin) {
  const int tid   = threadIdx.x;
  const int chain = blockIdx.x * 8 + (tid >> 5);  // 0..2047 = bh*32 + i
  const int j     = tid & 31;
  const int bh    = chain >> 5;
  const int i     = chain & 31;

  float S = S0[(size_t)bh * 1024 + i * 32 + j];

  const float* knp = kn + (size_t)bh * 32 + j;   // stride 2048 per t
  const float* vvp = vv + (size_t)bh * 32 + i;   // stride 2048 per t
  const float* bbp = bb + bh;                    // stride 64 per t
  float knc = knp[0];
  float vc  = vvp[0];
  float bc  = bbp[0];

  float* outp = out + chain;                     // stride 2048 per t

  for (int t = 0; t < T_STEPS; ++t) {
    // prefetch next step's statistics (clamped; uniform, S-independent)
    const int tn = (t + 1 < T_STEPS) ? (t + 1) : t;
    const float knn = knp[(size_t)tn * 2048];
    const float vn  = vvp[(size_t)tn * 2048];
    const float bn  = bbp[(size_t)tn * 64];

    // retrieved[i] = sum_j S[i][j] * knorm[j]
    float r = S * knc;
    r += __shfl_xor(r, 1);
    r += __shfl_xor(r, 2);
    r += __shfl_xor(r, 4);
    r += __shfl_xor(r, 8);
    r += __shfl_xor(r, 16);

    const float delta = vc - r;
    S = fast_tanh(bc * S + delta * knc);

    // Sq[i] = sum_j S_new[i][j] * knorm[j]
    float q = S * knc;
    q += __shfl_xor(q, 1);
    q += __shfl_xor(q, 2);
    q += __shfl_xor(q, 4);
    q += __shfl_xor(q, 8);
    q += __shfl_xor(q, 16);

    const float sg = fast_sigmoid(q);
    const float o  = q * q * sg;                 // Sq * silu(Sq)
    if (j == 0) outp[(size_t)t * 2048] = o;

    knc = knn; vc = vn; bc = bn;
  }

  Sfin[(size_t)bh * 1024 + i * 32 + j] = S;
}

extern "C" void kernel_launch(void* const* d_in, const int* in_sizes, int n_in,
                              void* d_out, int out_size, void* d_ws, size_t ws_size,
                              hipStream_t stream) {
  const float* x     = (const float*)d_in[0];   // [1024, 8, 8192] f32
  const float* S0    = (const float*)d_in[1];   // [8, 8, 32, 32] f32
  const float* scale = (const float*)d_in[2];   // scalar
  const float* bias  = (const float*)d_in[3];   // scalar
  float* out = (float*)d_out;                   // output [1024,8,256] then S_final [8,8,32,32]

  float* kn = (float*)d_ws;                     // [65536][32]
  float* vv = kn + (size_t)NTILE * 32;          // [65536][32]
  float* bb = vv + (size_t)NTILE * 32;          // [65536]
  // total ws use: 65536*(32+32+1)*4 B = ~16.3 MB

  stats_kernel<<<NTILE, 256, 0, stream>>>(x, scale, bias, kn, vv, bb);

  float* Sfin = out + (size_t)T_STEPS * 2048;   // 2,097,152 floats of output
  scan_kernel<<<NCHAIN / 8, 256, 0, stream>>>(S0, kn, vv, bb, out, Sfin);
}

// Round 2
// 568.498 us; speedup vs baseline: 1.5290x; 1.5290x over previous
//
#include <hip/hip_runtime.h>
#include <math.h>

// Problem constants: T=1024, B=8, H=8, N=32. D = H*N*N = 8192.
#define T_STEPS 1024
#define NBH     64          // B*H
#define NTILE   65536       // T*B*H
#define NCHAIN  2048        // B*H*N independent row-chains
#define UNROLL  8

static __device__ __forceinline__ float fast_rcp(float x) {
  return __builtin_amdgcn_rcpf(x);
}
static __device__ __forceinline__ float fast_sigmoid(float x) {
  return fast_rcp(1.0f + __expf(-x));
}
static __device__ __forceinline__ float fast_tanh(float x) {
  // tanh(x) = 1 - 2/(1+e^{2x}); exp->inf gives 1, exp->0 gives -1
  return 1.0f - 2.0f * fast_rcp(1.0f + __expf(2.0f * x));
}

// DPP add: x + lane-permuted(x). CTRL is a compile-time DPP control.
template <int CTRL>
static __device__ __forceinline__ float dpp_add(float x) {
  int y = __builtin_amdgcn_update_dpp(0, __float_as_int(x), CTRL, 0xF, 0xF, true);
  return x + __int_as_float(y);
}

// Butterfly sum over each 32-lane half-wave; result in all 32 lanes.
// Levels 1,2: quad_perm xor; 4,8: row mirrors (row=16 on CDNA);
// 16: ds_swizzle bitmode xor16 (operates within 32-lane groups).
static __device__ __forceinline__ float red32(float x) {
  x = dpp_add<0xB1>(x);    // quad_perm(1,0,3,2)  == xor 1
  x = dpp_add<0x4E>(x);    // quad_perm(2,3,0,1)  == xor 2
  x = dpp_add<0x141>(x);   // row_half_mirror     (exchanges quads in 8-group)
  x = dpp_add<0x140>(x);   // row_mirror          (exchanges 8-groups in 16)
  int y = __builtin_amdgcn_ds_swizzle(__float_as_int(x), 0x401F);  // xor 16
  return x + __int_as_float(y);
}

// ---------------------------------------------------------------------------
// Phase A: per-(t,b,h) tile statistics. ONE WAVE per 32x32 tile, no LDS, no
// __syncthreads. Grid-stride over 65536 tiles. Outputs transposed to
// [bh][t][...] layout for t-contiguous reads in the scan.
// Lane l (0..63): m = l&7 (col group, cols 4m..4m+3), g = l>>3 (row group).
// Loads float4 at indices l, l+64, l+128, l+192 -> rows g, g+8, g+16, g+24.
// ---------------------------------------------------------------------------
__global__ __launch_bounds__(256) void stats_kernel(
    const float* __restrict__ x, const float* __restrict__ scale_p,
    const float* __restrict__ bias_p, float* __restrict__ knT,
    float* __restrict__ vvT, float* __restrict__ bbT) {
  const int tid = threadIdx.x;
  const int l   = tid & 63;
  const int m   = l & 7;
  const int g   = l >> 3;
  const int wid    = (blockIdx.x * blockDim.x + tid) >> 6;
  const int nwaves = (gridDim.x * blockDim.x) >> 6;
  const float sc = scale_p[0], bi = bias_p[0];

  for (int tile = wid; tile < NTILE; tile += nwaves) {
    const int t  = tile >> 6;        // tile = t*64 + bh
    const int bh = tile & 63;
    const float4* xp = (const float4*)(x + (size_t)tile * 1024);
    const float4 a0 = xp[l];
    const float4 a1 = xp[l + 64];
    const float4 a2 = xp[l + 128];
    const float4 a3 = xp[l + 192];

    // row partials (rows g+8p over cols 4m..4m+3); reduce over m: xor 1,2,4
    float r0 = (a0.x + a0.y) + (a0.z + a0.w);
    float r1 = (a1.x + a1.y) + (a1.z + a1.w);
    float r2 = (a2.x + a2.y) + (a2.z + a2.w);
    float r3 = (a3.x + a3.y) + (a3.z + a3.w);
    r0 += __shfl_xor(r0, 1); r1 += __shfl_xor(r1, 1);
    r2 += __shfl_xor(r2, 1); r3 += __shfl_xor(r3, 1);
    r0 += __shfl_xor(r0, 2); r1 += __shfl_xor(r1, 2);
    r2 += __shfl_xor(r2, 2); r3 += __shfl_xor(r3, 2);
    r0 += __shfl_xor(r0, 4); r1 += __shfl_xor(r1, 4);
    r2 += __shfl_xor(r2, 4); r3 += __shfl_xor(r3, 4);
    // now r0..r3 = full row sums for rows g, g+8, g+16, g+24 (all lanes)

    // col partials (cols 4m..4m+3 over rows g+8p); reduce over g: xor 8,16,32
    float c0 = a0.x + a1.x + a2.x + a3.x;
    float c1 = a0.y + a1.y + a2.y + a3.y;
    float c2 = a0.z + a1.z + a2.z + a3.z;
    float c3 = a0.w + a1.w + a2.w + a3.w;
    c0 += __shfl_xor(c0, 8);  c1 += __shfl_xor(c1, 8);
    c2 += __shfl_xor(c2, 8);  c3 += __shfl_xor(c3, 8);
    c0 += __shfl_xor(c0, 16); c1 += __shfl_xor(c1, 16);
    c2 += __shfl_xor(c2, 16); c3 += __shfl_xor(c3, 16);
    c0 += __shfl_xor(c0, 32); c1 += __shfl_xor(c1, 32);
    c2 += __shfl_xor(c2, 32); c3 += __shfl_xor(c3, 32);
    // c0..c3 = full col sums for cols 4m..4m+3 (all lanes)

    // ||k||^2 and sum(k): per-lane partials over rows {g+8p}, reduce over g
    float t1 = (r0 + r1) + (r2 + r3);
    float t2 = (r0 * r0 + r1 * r1) + (r2 * r2 + r3 * r3);
    t1 += __shfl_xor(t1, 8);  t2 += __shfl_xor(t2, 8);
    t1 += __shfl_xor(t1, 16); t2 += __shfl_xor(t2, 16);
    t1 += __shfl_xor(t1, 32); t2 += __shfl_xor(t2, 32);
    const float sumk  = t1 * (1.0f / 32.0f);           // sum of row means
    const float norm  = sqrtf(t2) * (1.0f / 32.0f);    // ||k||, k = rowsum/32
    const float ks    = (1.0f / 32.0f) * fast_rcp(norm + 1e-6f);

    const size_t rec = ((size_t)bh * T_STEPS + t) * 32;
    if (m == 0) {           // 8 lanes, g = 0..7: write knorm rows g+8p
      float* kp = knT + rec + g;
      kp[0]  = r0 * ks;
      kp[8]  = r1 * ks;
      kp[16] = r2 * ks;
      kp[24] = r3 * ks;
    }
    if (l < 8) {            // lanes 0..7 (g==0, m==l): write v cols 4m..4m+3
      float4 vq;
      vq.x = c0 * (1.0f / 32.0f); vq.y = c1 * (1.0f / 32.0f);
      vq.z = c2 * (1.0f / 32.0f); vq.w = c3 * (1.0f / 32.0f);
      ((float4*)(vvT + rec))[m] = vq;
    }
    if (l == 0) {
      const float mean = sumk * (1.0f / 32.0f);
      bbT[(size_t)bh * T_STEPS + t] = fast_sigmoid(sc * mean + bi);
    }
  }
}

// ---------------------------------------------------------------------------
// Phase B: serial scan. 2048 independent row-chains (b,h,i), one 32-lane
// half-wave per chain (lane = column j). Stats in [bh][t] layout -> chain
// loads are t-contiguous; 8-step register ring hides memory latency.
// ---------------------------------------------------------------------------
__global__ __launch_bounds__(256) void scan_kernel(
    const float* __restrict__ S0, const float* __restrict__ knT,
    const float* __restrict__ vvT, const float* __restrict__ bbT,
    float* __restrict__ out, float* __restrict__ Sfin) {
  const int tid   = threadIdx.x;
  const int chain = blockIdx.x * 8 + (tid >> 5);  // 0..2047 = bh*32 + i
  const int j     = tid & 31;
  const int bh    = chain >> 5;
  const int i     = chain & 31;

  float S = S0[(size_t)bh * 1024 + i * 32 + j];

  const float* knp = knT + (size_t)bh * T_STEPS * 32 + j;  // +32 per t
  const float* vvp = vvT + (size_t)bh * T_STEPS * 32 + i;  // +32 per t
  const float* bbp = bbT + (size_t)bh * T_STEPS;           // +1 per t

  float rkn[UNROLL], rv[UNROLL], rb[UNROLL];
#pragma unroll
  for (int u = 0; u < UNROLL; ++u) {
    rkn[u] = knp[u * 32];
    rv[u]  = vvp[u * 32];
    rb[u]  = bbp[u];
  }

  float* outp = out + chain;                               // +2048 per t

  for (int t0 = 0; t0 < T_STEPS; t0 += UNROLL) {
    // issue next block's loads (S-independent; hidden behind 8 steps)
    float nkn[UNROLL], nv[UNROLL], nb[UNROLL];
#pragma unroll
    for (int u = 0; u < UNROLL; ++u) {
      int tn = t0 + UNROLL + u;
      tn = tn < T_STEPS ? tn : (T_STEPS - 1);
      nkn[u] = knp[(size_t)tn * 32];
      nv[u]  = vvp[(size_t)tn * 32];
      nb[u]  = bbp[tn];
    }
#pragma unroll
    for (int u = 0; u < UNROLL; ++u) {
      const float knc = rkn[u], vc = rv[u], bc = rb[u];
      // retrieved[i] = sum_j S[i][j]*knorm[j]  (critical path)
      const float r = red32(S * knc);
      S = fast_tanh(bc * S + (vc - r) * knc);
      // Sq -> output (off the S critical path; overlaps next step's r)
      const float q  = red32(S * knc);
      const float o  = q * q * fast_sigmoid(q);
      if (j == 0) outp[(size_t)(t0 + u) * 2048] = o;
    }
#pragma unroll
    for (int u = 0; u < UNROLL; ++u) {
      rkn[u] = nkn[u]; rv[u] = nv[u]; rb[u] = nb[u];
    }
  }

  Sfin[(size_t)bh * 1024 + i * 32 + j] = S;
}

extern "C" void kernel_launch(void* const* d_in, const int* in_sizes, int n_in,
                              void* d_out, int out_size, void* d_ws, size_t ws_size,
                              hipStream_t stream) {
  const float* x     = (const float*)d_in[0];   // [1024, 8, 8192] f32
  const float* S0    = (const float*)d_in[1];   // [8, 8, 32, 32] f32
  const float* scale = (const float*)d_in[2];   // scalar
  const float* bias  = (const float*)d_in[3];   // scalar
  float* out = (float*)d_out;                   // [1024,8,256] then S_final

  float* knT = (float*)d_ws;                    // [64][1024][32]
  float* vvT = knT + (size_t)NTILE * 32;        // [64][1024][32]
  float* bbT = vvT + (size_t)NTILE * 32;        // [64][1024]
  // total ws use: 65536*(32+32+1)*4 B = ~16.3 MB

  stats_kernel<<<2048, 256, 0, stream>>>(x, scale, bias, knT, vvT, bbT);

  float* Sfin = out + (size_t)T_STEPS * 2048;   // 2,097,152 floats of output
  scan_kernel<<<NCHAIN / 8, 256, 0, stream>>>(S0, knT, vvT, bbT, out, Sfin);
}

// Round 3
// 493.741 us; speedup vs baseline: 1.7605x; 1.1514x over previous
//
#include <hip/hip_runtime.h>
#include <math.h>

// Problem constants: T=1024, B=8, H=8, N=32. D = H*N*N = 8192.
#define T_STEPS 1024
#define NBH     64          // B*H
#define NTILE   65536       // T*B*H

static __device__ __forceinline__ float fast_rcp(float x) {
  return __builtin_amdgcn_rcpf(x);
}
static __device__ __forceinline__ float fast_sigmoid(float x) {
  return fast_rcp(1.0f + __expf(-x));
}
static __device__ __forceinline__ float fast_tanh(float x) {
  // tanh(x) = 1 - 2/(1+e^{2x}); exp->inf gives 1, exp->0 gives -1
  return 1.0f - 2.0f * fast_rcp(1.0f + __expf(2.0f * x));
}

// DPP add: x + lane-permuted(x). CTRL is a compile-time DPP control.
template <int CTRL>
static __device__ __forceinline__ float dpp_add(float x) {
  int y = __builtin_amdgcn_update_dpp(0, __float_as_int(x), CTRL, 0xF, 0xF, true);
  return x + __int_as_float(y);
}

// Butterfly sum over each 16-lane group; result in all 16 lanes.
// Pure DPP (VALU pipe) — no ds_swizzle, no lgkmcnt in the scan loop.
static __device__ __forceinline__ float red16(float x) {
  x = dpp_add<0xB1>(x);    // quad_perm(1,0,3,2)  == xor 1
  x = dpp_add<0x4E>(x);    // quad_perm(2,3,0,1)  == xor 2
  x = dpp_add<0x141>(x);   // row_half_mirror     == xor 4 (post-reduction)
  x = dpp_add<0x140>(x);   // row_mirror          == xor 8 (post-reduction)
  return x;
}

// ---------------------------------------------------------------------------
// Phase A: per-(t,b,h) tile statistics. One wave per tile, grid-stride.
// Outputs in t-MAJOR layout for the scan's streaming prefetch:
//   knT2[bh][elem][t], vvT2[bh][elem][t], bbT2[bh][t].
// ---------------------------------------------------------------------------
__global__ __launch_bounds__(256) void stats_kernel(
    const float* __restrict__ x, const float* __restrict__ scale_p,
    const float* __restrict__ bias_p, float* __restrict__ knT2,
    float* __restrict__ vvT2, float* __restrict__ bbT2) {
  const int tid = threadIdx.x;
  const int l   = tid & 63;
  const int m   = l & 7;
  const int g   = l >> 3;
  const int wid    = (blockIdx.x * blockDim.x + tid) >> 6;
  const int nwaves = (gridDim.x * blockDim.x) >> 6;
  const float sc = scale_p[0], bi = bias_p[0];

  for (int tile = wid; tile < NTILE; tile += nwaves) {
    const int t  = tile >> 6;        // tile = t*64 + bh
    const int bh = tile & 63;
    const float4* xp = (const float4*)(x + (size_t)tile * 1024);
    const float4 a0 = xp[l];
    const float4 a1 = xp[l + 64];
    const float4 a2 = xp[l + 128];
    const float4 a3 = xp[l + 192];

    // row partials (rows g+8p over cols 4m..4m+3); reduce over m: xor 1,2,4
    float r0 = (a0.x + a0.y) + (a0.z + a0.w);
    float r1 = (a1.x + a1.y) + (a1.z + a1.w);
    float r2 = (a2.x + a2.y) + (a2.z + a2.w);
    float r3 = (a3.x + a3.y) + (a3.z + a3.w);
    r0 += __shfl_xor(r0, 1); r1 += __shfl_xor(r1, 1);
    r2 += __shfl_xor(r2, 1); r3 += __shfl_xor(r3, 1);
    r0 += __shfl_xor(r0, 2); r1 += __shfl_xor(r1, 2);
    r2 += __shfl_xor(r2, 2); r3 += __shfl_xor(r3, 2);
    r0 += __shfl_xor(r0, 4); r1 += __shfl_xor(r1, 4);
    r2 += __shfl_xor(r2, 4); r3 += __shfl_xor(r3, 4);
    // r0..r3 = full row sums for rows g, g+8, g+16, g+24 (all lanes)

    // col partials (cols 4m..4m+3 over rows g+8p); reduce over g: xor 8,16,32
    float c0 = a0.x + a1.x + a2.x + a3.x;
    float c1 = a0.y + a1.y + a2.y + a3.y;
    float c2 = a0.z + a1.z + a2.z + a3.z;
    float c3 = a0.w + a1.w + a2.w + a3.w;
    c0 += __shfl_xor(c0, 8);  c1 += __shfl_xor(c1, 8);
    c2 += __shfl_xor(c2, 8);  c3 += __shfl_xor(c3, 8);
    c0 += __shfl_xor(c0, 16); c1 += __shfl_xor(c1, 16);
    c2 += __shfl_xor(c2, 16); c3 += __shfl_xor(c3, 16);
    c0 += __shfl_xor(c0, 32); c1 += __shfl_xor(c1, 32);
    c2 += __shfl_xor(c2, 32); c3 += __shfl_xor(c3, 32);
    // c0..c3 = full col sums for cols 4m..4m+3 (all lanes)

    // ||k||^2 and sum(k): per-lane partials over rows {g+8p}, reduce over g
    float t1 = (r0 + r1) + (r2 + r3);
    float t2 = (r0 * r0 + r1 * r1) + (r2 * r2 + r3 * r3);
    t1 += __shfl_xor(t1, 8);  t2 += __shfl_xor(t2, 8);
    t1 += __shfl_xor(t1, 16); t2 += __shfl_xor(t2, 16);
    t1 += __shfl_xor(t1, 32); t2 += __shfl_xor(t2, 32);
    const float norm = sqrtf(t2) * (1.0f / 32.0f);     // ||k||, k = rowsum/32
    const float ks   = (1.0f / 32.0f) * fast_rcp(norm + 1e-6f);

    // t-major scatter stores (L2 merges: concurrent waves cover adjacent t)
    const size_t base = (size_t)bh * 32 * T_STEPS + t;
    if (m == 0) {           // 8 lanes, g = 0..7: knorm elements g+8p
      knT2[base + (size_t)(g)      * T_STEPS] = r0 * ks;
      knT2[base + (size_t)(g + 8)  * T_STEPS] = r1 * ks;
      knT2[base + (size_t)(g + 16) * T_STEPS] = r2 * ks;
      knT2[base + (size_t)(g + 24) * T_STEPS] = r3 * ks;
    }
    if (l < 8) {            // lanes 0..7 (m==l): v elements 4m..4m+3
      vvT2[base + (size_t)(4 * m)     * T_STEPS] = c0 * (1.0f / 32.0f);
      vvT2[base + (size_t)(4 * m + 1) * T_STEPS] = c1 * (1.0f / 32.0f);
      vvT2[base + (size_t)(4 * m + 2) * T_STEPS] = c2 * (1.0f / 32.0f);
      vvT2[base + (size_t)(4 * m + 3) * T_STEPS] = c3 * (1.0f / 32.0f);
    }
    if (l == 0) {
      const float mean = t1 * (1.0f / 1024.0f);
      bbT2[(size_t)bh * T_STEPS + t] = fast_sigmoid(sc * mean + bi);
    }
  }
}

// ---------------------------------------------------------------------------
// Phase B: serial scan. 2048 chains (bh,i); 16 lanes per chain, lane owns
// cols {2s, 2s+1}. Reduction = 4 pure-DPP adds (no LDS pipe in the loop).
// Stats streamed t-major with explicit 16-step double buffering.
// 512 waves = 128 blocks x 256 threads.
// ---------------------------------------------------------------------------
__global__ __launch_bounds__(256, 1) void scan_kernel(
    const float* __restrict__ S0, const float* __restrict__ knT2,
    const float* __restrict__ vvT2, const float* __restrict__ bbT2,
    float* __restrict__ out, float* __restrict__ Sfin) {
  const int tid  = threadIdx.x;
  const int lane = tid & 63;
  const int g    = lane >> 4;                    // group in wave (0..3)
  const int s    = lane & 15;                    // lane in group
  const int w    = blockIdx.x * 4 + (tid >> 6);  // global wave 0..511
  const int bh   = w >> 3;                       // 0..63
  const int i    = (w & 7) * 4 + g;              // 0..31
  const int chain = bh * 32 + i;

  const float2 sini = *(const float2*)(S0 + (size_t)bh * 1024 + i * 32 + 2 * s);
  float Sa = sini.x, Sb = sini.y;

  const float* kn0p = knT2 + ((size_t)bh * 32 + 2 * s) * T_STEPS;
  const float* kn1p = kn0p + T_STEPS;
  const float* vp   = vvT2 + ((size_t)bh * 32 + i) * T_STEPS;
  const float* bp   = bbT2 + (size_t)bh * T_STEPS;

  float Ak0[16], Ak1[16], Av[16], Ab[16];
  float Bk0[16], Bk1[16], Bv[16], Bb[16];

#define LOAD_BLK(K0, K1, VV, BE, TOFF)                                    \
  do {                                                                    \
    const int _to = (TOFF);                                               \
    _Pragma("unroll")                                                     \
    for (int qq = 0; qq < 4; ++qq) {                                      \
      *(float4*)&K0[4 * qq] = *(const float4*)(kn0p + _to + 4 * qq);      \
      *(float4*)&K1[4 * qq] = *(const float4*)(kn1p + _to + 4 * qq);      \
      *(float4*)&VV[4 * qq] = *(const float4*)(vp   + _to + 4 * qq);      \
      *(float4*)&BE[4 * qq] = *(const float4*)(bp   + _to + 4 * qq);      \
    }                                                                     \
  } while (0)

#define STEP_BLK(K0, K1, VV, BE, TBASE)                                   \
  do {                                                                    \
    float oacc = 0.0f;                                                    \
    _Pragma("unroll")                                                     \
    for (int u = 0; u < 16; ++u) {                                        \
      const float c0 = K0[u], c1 = K1[u];                                 \
      float r = red16(Sa * c0 + Sb * c1);                                 \
      const float d  = VV[u] - r;                                         \
      const float bc = BE[u];                                             \
      Sa = fast_tanh(bc * Sa + d * c0);                                   \
      Sb = fast_tanh(bc * Sb + d * c1);                                   \
      float qv = red16(Sa * c0 + Sb * c1);                                \
      const float o = qv * qv * fast_sigmoid(qv);                         \
      oacc = (u == s) ? o : oacc;                                         \
    }                                                                     \
    outp[(size_t)((TBASE) + s) * 2048] = oacc;                            \
  } while (0)

  float* outp = out + chain;

  LOAD_BLK(Ak0, Ak1, Av, Ab, 0);                 // t = 0..15

  for (int t0 = 0; t0 < T_STEPS; t0 += 32) {
    const int tB = t0 + 16;                      // always < T_STEPS
    const int tA2 = (t0 + 32 < T_STEPS) ? t0 + 32 : t0;  // clamp (dead data)
    LOAD_BLK(Bk0, Bk1, Bv, Bb, tB);              // prefetch block B
    STEP_BLK(Ak0, Ak1, Av, Ab, t0);              // compute block A
    LOAD_BLK(Ak0, Ak1, Av, Ab, tA2);             // prefetch next block A
    STEP_BLK(Bk0, Bk1, Bv, Bb, tB);              // compute block B
  }

#undef LOAD_BLK
#undef STEP_BLK

  float2 sfin; sfin.x = Sa; sfin.y = Sb;
  *(float2*)(Sfin + (size_t)bh * 1024 + i * 32 + 2 * s) = sfin;
}

extern "C" void kernel_launch(void* const* d_in, const int* in_sizes, int n_in,
                              void* d_out, int out_size, void* d_ws, size_t ws_size,
                              hipStream_t stream) {
  const float* x     = (const float*)d_in[0];   // [1024, 8, 8192] f32
  const float* S0    = (const float*)d_in[1];   // [8, 8, 32, 32] f32
  const float* scale = (const float*)d_in[2];   // scalar
  const float* bias  = (const float*)d_in[3];   // scalar
  float* out = (float*)d_out;                   // [1024,8,256] then S_final

  float* knT2 = (float*)d_ws;                   // [64][32][1024]
  float* vvT2 = knT2 + (size_t)NTILE * 32;      // [64][32][1024]
  float* bbT2 = vvT2 + (size_t)NTILE * 32;      // [64][1024]
  // total ws use: ~16.3 MB

  stats_kernel<<<2048, 256, 0, stream>>>(x, scale, bias, knT2, vvT2, bbT2);

  float* Sfin = out + (size_t)T_STEPS * 2048;   // after 2,097,152 output floats
  scan_kernel<<<128, 256, 0, stream>>>(S0, knT2, vvT2, bbT2, out, Sfin);
}

// Round 4
// 465.763 us; speedup vs baseline: 1.8662x; 1.0601x over previous
//
#include <hip/hip_runtime.h>
#include <math.h>

// Problem constants: T=1024, B=8, H=8, N=32. D = H*N*N = 8192.
#define T_STEPS 1024
#define NBH     64          // B*H
#define NTILE   65536       // T*B*H

static __device__ __forceinline__ float fast_rcp(float x) {
  return __builtin_amdgcn_rcpf(x);
}
static __device__ __forceinline__ float fast_sigmoid(float x) {
  return fast_rcp(1.0f + __expf(-x));
}
// tanh(x) where y = 2x is passed: tanh = 1 - 2/(1+e^{2x})
static __device__ __forceinline__ float fast_tanh2(float y) {
  return 1.0f - 2.0f * fast_rcp(1.0f + __expf(y));
}

// DPP add: x + lane-permuted(x). CTRL is a compile-time DPP control.
template <int CTRL>
static __device__ __forceinline__ float dpp_add(float x) {
  int y = __builtin_amdgcn_update_dpp(0, __float_as_int(x), CTRL, 0xF, 0xF, true);
  return x + __int_as_float(y);
}

// Butterfly sum over each 16-lane group; result in all 16 lanes. Pure DPP.
static __device__ __forceinline__ float red16(float x) {
  x = dpp_add<0xB1>(x);    // quad_perm(1,0,3,2)  == xor 1
  x = dpp_add<0x4E>(x);    // quad_perm(2,3,0,1)  == xor 2
  x = dpp_add<0x141>(x);   // row_half_mirror     == xor 4
  x = dpp_add<0x140>(x);   // row_mirror          == xor 8
  return x;
}

// ---------------------------------------------------------------------------
// Phase A: per-(t,b,h) tile statistics. One wave handles 16 consecutive t of
// one bh (4096 jobs). Per-tile reductions identical to verified R2/R3 code.
// Results staged in LDS [elem][16], flushed with coalesced dwordx4 stores to
// t-major layout: knT2[bh][elem][t], vvT2[bh][elem][t] (=2*v), bbT2[bh][t]
// (=2*beta).
// ---------------------------------------------------------------------------
__global__ __launch_bounds__(256) void stats_kernel(
    const float* __restrict__ x, const float* __restrict__ scale_p,
    const float* __restrict__ bias_p, float* __restrict__ knT2,
    float* __restrict__ vvT2, float* __restrict__ bbT2) {
  const int tid = threadIdx.x;
  const int l   = tid & 63;
  const int m   = l & 7;
  const int g   = l >> 3;
  const int wib = tid >> 6;                 // wave in block 0..3
  const int job = blockIdx.x * 4 + wib;     // 0..4095
  const int bh  = job >> 6;
  const int t0  = (job & 63) << 4;          // chunk of 16 t
  const float sc = scale_p[0], bi = bias_p[0];

  __shared__ float kn_s[4][512];            // [wave][elem*16 + tt]
  __shared__ float vv_s[4][512];
  __shared__ float bb_s[4][16];
  float* ks = kn_s[wib];
  float* vs = vv_s[wib];
  float* bs = bb_s[wib];

  // tile tt lives at x + ((t0+tt)*64 + bh)*1024 ; stride between tt = 65536
  const float4* xp = (const float4*)(x + ((size_t)t0 * 64 + bh) * 1024);
  // preload tile 0
  float4 a0 = xp[l], a1 = xp[l + 64], a2 = xp[l + 128], a3 = xp[l + 192];

  for (int tt = 0; tt < 16; ++tt) {
    float4 b0, b1, b2, b3;
    if (tt < 15) {
      const float4* xn = xp + (size_t)(tt + 1) * 16384;  // +64*1024 floats
      b0 = xn[l]; b1 = xn[l + 64]; b2 = xn[l + 128]; b3 = xn[l + 192];
    }

    // row partials; reduce over m: xor 1,2,4
    float r0 = (a0.x + a0.y) + (a0.z + a0.w);
    float r1 = (a1.x + a1.y) + (a1.z + a1.w);
    float r2 = (a2.x + a2.y) + (a2.z + a2.w);
    float r3 = (a3.x + a3.y) + (a3.z + a3.w);
    r0 += __shfl_xor(r0, 1); r1 += __shfl_xor(r1, 1);
    r2 += __shfl_xor(r2, 1); r3 += __shfl_xor(r3, 1);
    r0 += __shfl_xor(r0, 2); r1 += __shfl_xor(r1, 2);
    r2 += __shfl_xor(r2, 2); r3 += __shfl_xor(r3, 2);
    r0 += __shfl_xor(r0, 4); r1 += __shfl_xor(r1, 4);
    r2 += __shfl_xor(r2, 4); r3 += __shfl_xor(r3, 4);
    // r0..r3 = row sums for rows g, g+8, g+16, g+24 (all lanes)

    // col partials; reduce over g: xor 8,16,32
    float c0 = a0.x + a1.x + a2.x + a3.x;
    float c1 = a0.y + a1.y + a2.y + a3.y;
    float c2 = a0.z + a1.z + a2.z + a3.z;
    float c3 = a0.w + a1.w + a2.w + a3.w;
    c0 += __shfl_xor(c0, 8);  c1 += __shfl_xor(c1, 8);
    c2 += __shfl_xor(c2, 8);  c3 += __shfl_xor(c3, 8);
    c0 += __shfl_xor(c0, 16); c1 += __shfl_xor(c1, 16);
    c2 += __shfl_xor(c2, 16); c3 += __shfl_xor(c3, 16);
    c0 += __shfl_xor(c0, 32); c1 += __shfl_xor(c1, 32);
    c2 += __shfl_xor(c2, 32); c3 += __shfl_xor(c3, 32);
    // c0..c3 = col sums for cols 4m..4m+3 (all lanes)

    // sum(k), ||k||^2 over rows; reduce over g
    float t1 = (r0 + r1) + (r2 + r3);
    float t2 = (r0 * r0 + r1 * r1) + (r2 * r2 + r3 * r3);
    t1 += __shfl_xor(t1, 8);  t2 += __shfl_xor(t2, 8);
    t1 += __shfl_xor(t1, 16); t2 += __shfl_xor(t2, 16);
    t1 += __shfl_xor(t1, 32); t2 += __shfl_xor(t2, 32);
    const float norm = sqrtf(t2) * (1.0f / 32.0f);   // ||k||, k = rowsum/32
    const float kscl = (1.0f / 32.0f) * fast_rcp(norm + 1e-6f);

    if (m == 0) {          // 8 lanes: knorm elements g+8p for this tt
      ks[(g)      * 16 + tt] = r0 * kscl;
      ks[(g + 8)  * 16 + tt] = r1 * kscl;
      ks[(g + 16) * 16 + tt] = r2 * kscl;
      ks[(g + 24) * 16 + tt] = r3 * kscl;
    }
    if (l < 8) {           // lanes 0..7 (m==l): V2 = 2*colmean = colsum/16
      vs[(4 * m)     * 16 + tt] = c0 * (1.0f / 16.0f);
      vs[(4 * m + 1) * 16 + tt] = c1 * (1.0f / 16.0f);
      vs[(4 * m + 2) * 16 + tt] = c2 * (1.0f / 16.0f);
      vs[(4 * m + 3) * 16 + tt] = c3 * (1.0f / 16.0f);
    }
    if (l == 0) {          // B2 = 2*beta
      const float mean = t1 * (1.0f / 1024.0f);
      bs[tt] = 2.0f * fast_sigmoid(sc * mean + bi);
    }

    a0 = b0; a1 = b1; a2 = b2; a3 = b3;
  }

  // flush (same wave wrote the LDS; lgkmcnt ordering only, no barrier needed)
  const size_t rowbase = (size_t)bh * 32 * T_STEPS + t0;
#pragma unroll
  for (int rep = 0; rep < 2; ++rep) {
    const int c = l + rep * 64;       // chunk 0..127
    const int e = c >> 2;             // elem 0..31
    const int q = c & 3;              // quarter of the 16-t run
    const float4 kv = *(const float4*)&ks[e * 16 + q * 4];
    const float4 vv = *(const float4*)&vs[e * 16 + q * 4];
    *(float4*)(knT2 + rowbase + (size_t)e * T_STEPS + q * 4) = kv;
    *(float4*)(vvT2 + rowbase + (size_t)e * T_STEPS + q * 4) = vv;
  }
  if (l < 4) {
    const float4 bv = *(const float4*)&bs[l * 4];
    *(float4*)(bbT2 + (size_t)bh * T_STEPS + t0 + l * 4) = bv;
  }
}

// ---------------------------------------------------------------------------
// Phase B: serial scan. 2048 chains (bh,i); 16 lanes per chain, lane owns
// cols {2s, 2s+1}. Reduction = 4 pure-DPP adds. Stats streamed t-major with
// 16-step double buffering. vv holds V2=2v, bb holds B2=2*beta so the tanh
// argument is B2*S + (V2-2r)*kn with no extra doubling on the serial chain.
// ---------------------------------------------------------------------------
__global__ __launch_bounds__(256, 1) void scan_kernel(
    const float* __restrict__ S0, const float* __restrict__ knT2,
    const float* __restrict__ vvT2, const float* __restrict__ bbT2,
    float* __restrict__ out, float* __restrict__ Sfin) {
  const int tid  = threadIdx.x;
  const int lane = tid & 63;
  const int g    = lane >> 4;                    // group in wave (0..3)
  const int s    = lane & 15;                    // lane in group
  const int w    = blockIdx.x * 4 + (tid >> 6);  // global wave 0..511
  const int bh   = w >> 3;                       // 0..63
  const int i    = (w & 7) * 4 + g;              // 0..31
  const int chain = bh * 32 + i;

  const float2 sini = *(const float2*)(S0 + (size_t)bh * 1024 + i * 32 + 2 * s);
  float Sa = sini.x, Sb = sini.y;

  const float* kn0p = knT2 + ((size_t)bh * 32 + 2 * s) * T_STEPS;
  const float* kn1p = kn0p + T_STEPS;
  const float* vp   = vvT2 + ((size_t)bh * 32 + i) * T_STEPS;
  const float* bp   = bbT2 + (size_t)bh * T_STEPS;

  float Ak0[16], Ak1[16], Av[16], Ab[16];
  float Bk0[16], Bk1[16], Bv[16], Bb[16];

#define LOAD_BLK(K0, K1, VV, BE, TOFF)                                    \
  do {                                                                    \
    const int _to = (TOFF);                                               \
    _Pragma("unroll")                                                     \
    for (int qq = 0; qq < 4; ++qq) {                                      \
      *(float4*)&K0[4 * qq] = *(const float4*)(kn0p + _to + 4 * qq);      \
      *(float4*)&K1[4 * qq] = *(const float4*)(kn1p + _to + 4 * qq);      \
      *(float4*)&VV[4 * qq] = *(const float4*)(vp   + _to + 4 * qq);      \
      *(float4*)&BE[4 * qq] = *(const float4*)(bp   + _to + 4 * qq);      \
    }                                                                     \
  } while (0)

#define STEP_BLK(K0, K1, VV, BE, TBASE)                                   \
  do {                                                                    \
    float oacc = 0.0f;                                                    \
    _Pragma("unroll")                                                     \
    for (int u = 0; u < 16; ++u) {                                        \
      const float c0 = K0[u], c1 = K1[u];                                 \
      const float r  = red16(Sa * c0 + Sb * c1);                          \
      const float D2 = fmaf(-2.0f, r, VV[u]);   /* 2*(v - r) */           \
      const float B2 = BE[u];                                             \
      Sa = fast_tanh2(fmaf(B2, Sa, D2 * c0));                             \
      Sb = fast_tanh2(fmaf(B2, Sb, D2 * c1));                             \
      const float qv = red16(Sa * c0 + Sb * c1);                          \
      const float o  = qv * qv * fast_sigmoid(qv);                        \
      oacc = (u == s) ? o : oacc;                                         \
    }                                                                     \
    outp[(size_t)((TBASE) + s) * 2048] = oacc;                            \
  } while (0)

  float* outp = out + chain;

  LOAD_BLK(Ak0, Ak1, Av, Ab, 0);                 // t = 0..15

  for (int t0 = 0; t0 < T_STEPS; t0 += 32) {
    const int tB = t0 + 16;                      // always < T_STEPS
    const int tA2 = (t0 + 32 < T_STEPS) ? t0 + 32 : t0;  // clamp (dead data)
    LOAD_BLK(Bk0, Bk1, Bv, Bb, tB);              // prefetch block B
    STEP_BLK(Ak0, Ak1, Av, Ab, t0);              // compute block A
    LOAD_BLK(Ak0, Ak1, Av, Ab, tA2);             // prefetch next block A
    STEP_BLK(Bk0, Bk1, Bv, Bb, tB);              // compute block B
  }

#undef LOAD_BLK
#undef STEP_BLK

  float2 sfin; sfin.x = Sa; sfin.y = Sb;
  *(float2*)(Sfin + (size_t)bh * 1024 + i * 32 + 2 * s) = sfin;
}

extern "C" void kernel_launch(void* const* d_in, const int* in_sizes, int n_in,
                              void* d_out, int out_size, void* d_ws, size_t ws_size,
                              hipStream_t stream) {
  const float* x     = (const float*)d_in[0];   // [1024, 8, 8192] f32
  const float* S0    = (const float*)d_in[1];   // [8, 8, 32, 32] f32
  const float* scale = (const float*)d_in[2];   // scalar
  const float* bias  = (const float*)d_in[3];   // scalar
  float* out = (float*)d_out;                   // [1024,8,256] then S_final

  float* knT2 = (float*)d_ws;                   // [64][32][1024]
  float* vvT2 = knT2 + (size_t)NTILE * 32;      // [64][32][1024]  (2*v)
  float* bbT2 = vvT2 + (size_t)NTILE * 32;      // [64][1024]      (2*beta)
  // total ws use: ~16.3 MB

  stats_kernel<<<1024, 256, 0, stream>>>(x, scale, bias, knT2, vvT2, bbT2);

  float* Sfin = out + (size_t)T_STEPS * 2048;   // after 2,097,152 output floats
  scan_kernel<<<128, 256, 0, stream>>>(S0, knT2, vvT2, bbT2, out, Sfin);
}